// Round 3
// baseline (266.443 us; speedup 1.0000x reference)
//
#include <hip/hip_runtime.h>
#include <stdint.h>

typedef __attribute__((ext_vector_type(8))) short short8;
typedef __attribute__((ext_vector_type(4))) float f32x4;
typedef unsigned short u16;

#define NBATCH 8
#define SLEN 1024
#define CDIM 512
#define NHEADS 8
#define HDIM 64
#define MROWS (NBATCH*SLEN)
#define NQKV (NHEADS*3*HDIM)   // 1536
#define QK_SCALE 0.35355339059327373f  // 64^-0.25

__device__ inline u16 f2bf(float f){
  union{float f; uint32_t i;} v; v.f=f;
  uint32_t r = v.i + 0x7fffu + ((v.i>>16)&1u);
  return (u16)(r>>16);
}

// ---------------- weight prep: cast + transpose to (N, K) bf16 ----------------
__global__ void prep_wqkv(const float* __restrict__ w, u16* __restrict__ wt){
  int idx = blockIdx.x*256 + threadIdx.x;   // over 1536*512
  int n = idx >> 9, k2 = idx & 511;
  wt[idx] = f2bf(w[(size_t)k2*NQKV + n]);
}
__global__ void prep_wout(const float* __restrict__ w, u16* __restrict__ wt){
  int idx = blockIdx.x*256 + threadIdx.x;   // over 512*512
  int n = idx >> 9, k2 = idx & 511;
  wt[idx] = f2bf(w[(size_t)k2*CDIM + n]);
}

// ---------------- groupnorm stats: one block per (b,g) ----------------
__global__ __launch_bounds__(256) void gn_stats(const float* __restrict__ x, float* __restrict__ stats){
  int bid = blockIdx.x;            // b*32+g
  int b = bid >> 5, g = bid & 31;
  int t = threadIdx.x;
  const float* base = x + (size_t)b*SLEN*CDIM + g*16;
  float s1=0.f, s2=0.f;
  for (int s = t; s < SLEN; s += 256){
    const float4* p = (const float4*)(base + (size_t)s*CDIM);
    #pragma unroll
    for (int j=0;j<4;++j){
      float4 v = p[j];
      s1 += v.x+v.y+v.z+v.w;
      s2 += v.x*v.x + v.y*v.y + v.z*v.z + v.w*v.w;
    }
  }
  #pragma unroll
  for (int m=1;m<64;m<<=1){ s1 += __shfl_xor(s1,m); s2 += __shfl_xor(s2,m); }
  __shared__ float red[8];
  int wid = t>>6;
  if ((t&63)==0){ red[wid*2]=s1; red[wid*2+1]=s2; }
  __syncthreads();
  if (t==0){
    float a=0,c=0;
    #pragma unroll
    for (int w2=0;w2<4;++w2){ a+=red[w2*2]; c+=red[w2*2+1]; }
    float mean = a*(1.f/16384.f);
    float var  = c*(1.f/16384.f) - mean*mean;
    stats[bid*2]   = mean;
    stats[bid*2+1] = rsqrtf(var + 1e-5f);
  }
}

// ---------------- normalize + cast to bf16 ----------------
__global__ __launch_bounds__(256) void norm_cast(const float* __restrict__ x, const float* __restrict__ stats,
                        const float* __restrict__ scale, const float* __restrict__ bias,
                        u16* __restrict__ xn){
  int idx = blockIdx.x*256 + threadIdx.x;   // over 8192*32 (one 16-ch group per thread)
  int m = idx >> 5, g = idx & 31;
  int b = m >> 10;
  float mean = stats[(b*32+g)*2];
  float rstd = stats[(b*32+g)*2+1];
  const float* xp = x + (size_t)m*CDIM + g*16;
  const float* sp = scale + g*16;
  const float* bp = bias + g*16;
  short8 o0, o1;
  #pragma unroll
  for (int j=0;j<16;++j){
    float v = (xp[j]-mean)*rstd*sp[j] + bp[j];
    if (j<8) o0[j] = (short)f2bf(v); else o1[j-8] = (short)f2bf(v);
  }
  short8* dst = (short8*)(xn + (size_t)m*CDIM + g*16);
  dst[0]=o0; dst[1]=o1;
}

// ---------------- GEMM: C = A(MxK) * Bt(NxK)^T, bf16 in, fp32 acc ----------------
#define BM 128
#define BN 128
#define BK 64

template<int EPI>
__global__ __launch_bounds__(256, 3) void gemm_bf16(
    const u16* __restrict__ A, const u16* __restrict__ Bt,
    const float* __restrict__ bias, const float* __restrict__ resid,
    float* __restrict__ outF,
    u16* __restrict__ qb, u16* __restrict__ kb, u16* __restrict__ vtb)
{
  const int K = CDIM;
  int t = threadIdx.x;
  int l = t & 63, wid = t >> 6;
  int g = l >> 4, c = l & 15;
  int wr = wid >> 1, wc = wid & 1;
  int m0 = blockIdx.y * BM, n0 = blockIdx.x * BN;

  __shared__ __attribute__((aligned(16))) u16 lsA[BM*BK];
  __shared__ __attribute__((aligned(16))) u16 lsB[BN*BK];
  char* lsAc = (char*)lsA; char* lsBc = (char*)lsB;

  f32x4 acc[4][4];
  #pragma unroll
  for (int i=0;i<4;++i)
    #pragma unroll
    for(int j=0;j<4;++j) acc[i][j] = (f32x4)0.f;

  int srow = t >> 3;      // 0..31
  int ssl  = t & 7;       // 16B slot within 64-col row
  uint4 ra[4], rb[4];
  const int KT = K / BK;  // 8
  #pragma unroll
  for (int i=0;i<4;++i){
    int row = srow + 32*i;
    ra[i] = *(const uint4*)(A  + (size_t)(m0+row)*K + ssl*8);
    rb[i] = *(const uint4*)(Bt + (size_t)(n0+row)*K + ssl*8);
  }
  for (int kt=0; kt<KT; ++kt){
    __syncthreads();
    #pragma unroll
    for (int i=0;i<4;++i){
      int row = srow + 32*i;
      int sw = (ssl ^ (row & 7));
      *(uint4*)(lsAc + row*128 + sw*16) = ra[i];
      *(uint4*)(lsBc + row*128 + sw*16) = rb[i];
    }
    __syncthreads();
    if (kt+1 < KT){
      #pragma unroll
      for (int i=0;i<4;++i){
        int row = srow + 32*i;
        ra[i] = *(const uint4*)(A  + (size_t)(m0+row)*K + (kt+1)*BK + ssl*8);
        rb[i] = *(const uint4*)(Bt + (size_t)(n0+row)*K + (kt+1)*BK + ssl*8);
      }
    }
    #pragma unroll
    for (int kk=0; kk<2; ++kk){
      short8 af[4], bfr[4];
      #pragma unroll
      for (int i=0;i<4;++i){
        int rowA = wr*64 + i*16 + c;
        af[i]  = *(const short8*)(lsAc + rowA*128 + ((kk*4+g) ^ (rowA&7))*16);
        int rowB = wc*64 + i*16 + c;
        bfr[i] = *(const short8*)(lsBc + rowB*128 + ((kk*4+g) ^ (rowB&7))*16);
      }
      #pragma unroll
      for (int i=0;i<4;++i)
        #pragma unroll
        for (int j=0;j<4;++j)
          acc[i][j] = __builtin_amdgcn_mfma_f32_16x16x32_bf16(af[i], bfr[j], acc[i][j], 0,0,0);
    }
  }

  if (EPI == 0){
    int b = m0 >> 10;
    #pragma unroll
    for (int i=0;i<4;++i){
      int grow = m0 + wr*64 + i*16 + g*4;
      #pragma unroll
      for (int j=0;j<4;++j){
        int gcol = n0 + wc*64 + j*16 + c;
        int h = gcol / 192, jj = gcol % 192;
        float bv = bias[gcol];
        #pragma unroll
        for (int r=0;r<4;++r){
          int s = (grow + r) & (SLEN-1);
          float val = acc[i][j][r] + bv;
          if (jj < 64){
            qb[(((size_t)(b*NHEADS+h))*SLEN + s)*HDIM + jj] = f2bf(val*QK_SCALE);
          } else if (jj < 128){
            kb[(((size_t)(b*NHEADS+h))*SLEN + s)*HDIM + (jj-64)] = f2bf(val*QK_SCALE);
          } else {
            vtb[(((size_t)(b*NHEADS+h))*HDIM + (jj-128))*SLEN + s] = f2bf(val);
          }
        }
      }
    }
  } else {
    #pragma unroll
    for (int i=0;i<4;++i){
      int grow = m0 + wr*64 + i*16 + g*4;
      #pragma unroll
      for (int j=0;j<4;++j){
        int gcol = n0 + wc*64 + j*16 + c;
        float bv = bias[gcol];
        #pragma unroll
        for (int r=0;r<4;++r){
          size_t off = (size_t)(grow+r)*CDIM + gcol;
          outF[off] = (acc[i][j][r] + bv + resid[off]);  // SKIP_SCALE == 1.0
        }
      }
    }
  }
}

// ---------------- fused flash attention, key-split across 4 waves ----------------
// grid: 64 bh * 64 qtiles = 4096 blocks; block: 256 thr (4 waves).
// Each wave: same 16 q-rows, its own 256-key slice (4 tiles of 64).
// Partial (m,l,O) combined across waves via LDS at the end.
__global__ __launch_bounds__(256, 3) void attn_fused(const u16* __restrict__ qg,
  const u16* __restrict__ kg, const u16* __restrict__ vtg, u16* __restrict__ og)
{
  int blk = blockIdx.x;
  int bh = blk >> 6;         // 0..63
  int qt = blk & 63;         // 16-row q tile
  int t = threadIdx.x, l = t&63, wid = t>>6;
  int g = l>>4, c = l&15;
  int qbase = qt*16;

  // LDS: per-wave P buffer [16][88] u16 (2816 B each, 11264 total),
  // overlaid (after barrier) by combine buffers: co[4][16][64] f32 (16384) + cm/cl.
  __shared__ __attribute__((aligned(16))) char smem[17408];
  char* pb = smem + wid*2816;            // this wave's P buffer
  float* co = (float*)smem;              // [4][16][64]
  float* cm = (float*)(smem + 16384);    // [4][16]
  float* cl = (float*)(smem + 16640);    // [4][16]

  const u16* qp = qg + ((size_t)bh*SLEN + qbase)*HDIM;
  short8 aQ[2];
  #pragma unroll
  for (int kk=0;kk<2;++kk)
    aQ[kk] = *(const short8*)(qp + c*HDIM + kk*32 + g*8);

  float m_r[4], l_r[4];
  f32x4 oacc[4];
  #pragma unroll
  for (int r=0;r<4;++r){ m_r[r] = -1e30f; l_r[r]=0.f; }
  #pragma unroll
  for (int d=0;d<4;++d) oacc[d] = (f32x4)0.f;

  const u16* kbase = kg  + (size_t)bh*SLEN*HDIM + (size_t)wid*256*HDIM;
  const u16* vbase = vtg + (size_t)bh*HDIM*SLEN + wid*256;

  for (int kt=0; kt<4; ++kt){
    const u16* kp = kbase + (size_t)kt*64*HDIM;
    const u16* vp = vbase + kt*64;
    // QK^T
    f32x4 sc[4];
    #pragma unroll
    for (int s4=0;s4<4;++s4) sc[s4]=(f32x4)0.f;
    short8 bK[4][2];
    #pragma unroll
    for (int s4=0;s4<4;++s4)
      #pragma unroll
      for (int kk=0;kk<2;++kk)
        bK[s4][kk] = *(const short8*)(kp + (size_t)(s4*16+c)*HDIM + kk*32 + g*8);
    __builtin_amdgcn_s_setprio(1);
    #pragma unroll
    for (int s4=0;s4<4;++s4)
      #pragma unroll
      for (int kk=0;kk<2;++kk)
        sc[s4] = __builtin_amdgcn_mfma_f32_16x16x32_bf16(aQ[kk], bK[s4][kk], sc[s4], 0,0,0);
    __builtin_amdgcn_s_setprio(0);
    // issue V loads now so their latency hides under softmax VALU
    short8 bV[4][2];
    #pragma unroll
    for (int d=0;d<4;++d)
      #pragma unroll
      for (int kk=0;kk<2;++kk)
        bV[d][kk] = *(const short8*)(vp + (size_t)(d*16+c)*SLEN + kk*32 + g*8);
    // online softmax (rows live in 16-lane groups)
    float tm[4];
    #pragma unroll
    for (int r=0;r<4;++r)
      tm[r] = fmaxf(fmaxf(sc[0][r],sc[1][r]), fmaxf(sc[2][r],sc[3][r]));
    #pragma unroll
    for (int mk=1; mk<16; mk<<=1)
      #pragma unroll
      for (int r=0;r<4;++r) tm[r] = fmaxf(tm[r], __shfl_xor(tm[r], mk));
    float alpha[4], rs[4];
    #pragma unroll
    for (int r=0;r<4;++r){
      float mn = fmaxf(m_r[r], tm[r]);
      alpha[r] = __expf(m_r[r]-mn);
      m_r[r] = mn;
      rs[r]=0.f;
    }
    #pragma unroll
    for (int s4=0;s4<4;++s4)
      #pragma unroll
      for (int r=0;r<4;++r){
        float p = __expf(sc[s4][r]-m_r[r]);
        sc[s4][r]=p; rs[r]+=p;
      }
    #pragma unroll
    for (int mk=1; mk<16; mk<<=1)
      #pragma unroll
      for (int r=0;r<4;++r) rs[r] += __shfl_xor(rs[r], mk);
    #pragma unroll
    for (int r=0;r<4;++r) l_r[r] = l_r[r]*alpha[r] + rs[r];
    #pragma unroll
    for (int d=0;d<4;++d)
      #pragma unroll
      for (int r=0;r<4;++r) oacc[d][r]*=alpha[r];
    // P -> LDS (C/D layout) then re-read as A fragments
    #pragma unroll
    for (int s4=0;s4<4;++s4)
      #pragma unroll
      for (int r=0;r<4;++r)
        *(u16*)(pb + (g*4+r)*176 + (s4*16+c)*2) = f2bf(sc[s4][r]);
    short8 aP[2];
    #pragma unroll
    for (int kk=0;kk<2;++kk)
      aP[kk] = *(const short8*)(pb + c*176 + kk*64 + g*16);
    __builtin_amdgcn_s_setprio(1);
    #pragma unroll
    for (int d=0; d<4; ++d)
      #pragma unroll
      for (int kk=0;kk<2;++kk)
        oacc[d] = __builtin_amdgcn_mfma_f32_16x16x32_bf16(aP[kk], bV[d][kk], oacc[d], 0,0,0);
    __builtin_amdgcn_s_setprio(0);
  }

  // ---- combine partials across the 4 waves ----
  __syncthreads();   // everyone done with P buffers; safe to overlay
  #pragma unroll
  for (int r=0;r<4;++r){
    int row = g*4+r;
    if (c==0){ cm[wid*16+row] = m_r[r]; cl[wid*16+row] = l_r[r]; }
    #pragma unroll
    for (int d=0;d<4;++d)
      co[(wid*16+row)*64 + d*16 + c] = oacc[d][r];
  }
  __syncthreads();
  if (wid==0){
    int b = bh >> 3, h = bh & 7;
    #pragma unroll
    for (int r=0;r<4;++r){
      int row = g*4+r;
      float M = cm[row];
      #pragma unroll
      for (int w=1;w<4;++w) M = fmaxf(M, cm[w*16+row]);
      float L = 0.f, al[4];
      #pragma unroll
      for (int w=0;w<4;++w){ al[w] = __expf(cm[w*16+row]-M); L += al[w]*cl[w*16+row]; }
      float inv = 1.f / L;
      int s = qbase + row;
      size_t orow = ((size_t)b*SLEN + s)*CDIM + h*HDIM;
      #pragma unroll
      for (int d=0;d<4;++d){
        float o = 0.f;
        #pragma unroll
        for (int w=0;w<4;++w) o += al[w]*co[(w*16+row)*64 + d*16 + c];
        og[orow + d*16 + c] = f2bf(o*inv);
      }
    }
  }
}

extern "C" void kernel_launch(void* const* d_in, const int* in_sizes, int n_in,
                              void* d_out, int out_size, void* d_ws, size_t ws_size,
                              hipStream_t stream){
  const float* x      = (const float*)d_in[0];
  const float* nscale = (const float*)d_in[1];
  const float* nbias  = (const float*)d_in[2];
  const float* wqkv   = (const float*)d_in[3];
  const float* bqkv   = (const float*)d_in[4];
  const float* wout   = (const float*)d_in[5];
  const float* bout   = (const float*)d_in[6];
  float* out = (float*)d_out;

  char* ws = (char*)d_ws;
  size_t off = 0;
  auto alloc = [&](size_t bytes){ void* p = ws + off; off += (bytes + 255) & ~255ull; return p; };
  float* stats  = (float*)alloc(256*2*sizeof(float));
  u16* wqkv_t = (u16*)alloc((size_t)NQKV*CDIM*2);
  u16* wout_t = (u16*)alloc((size_t)CDIM*CDIM*2);
  u16* xn     = (u16*)alloc((size_t)MROWS*CDIM*2);
  u16* qb     = (u16*)alloc((size_t)MROWS*CDIM*2);
  u16* kb     = (u16*)alloc((size_t)MROWS*CDIM*2);
  u16* vtb    = (u16*)alloc((size_t)MROWS*CDIM*2);
  u16* ob     = (u16*)alloc((size_t)MROWS*CDIM*2);

  prep_wqkv<<<dim3((NQKV*CDIM)/256), dim3(256), 0, stream>>>(wqkv, wqkv_t);
  prep_wout<<<dim3((CDIM*CDIM)/256), dim3(256), 0, stream>>>(wout, wout_t);
  gn_stats <<<dim3(256), dim3(256), 0, stream>>>(x, stats);
  norm_cast<<<dim3((MROWS*32)/256), dim3(256), 0, stream>>>(x, stats, nscale, nbias, xn);
  gemm_bf16<0><<<dim3(NQKV/BN, MROWS/BM), dim3(256), 0, stream>>>(xn, wqkv_t, bqkv, nullptr, nullptr, qb, kb, vtb);
  attn_fused<<<dim3(64*64), dim3(256), 0, stream>>>(qb, kb, vtb, ob);
  gemm_bf16<1><<<dim3(CDIM/BN, MROWS/BM), dim3(256), 0, stream>>>(ob, wout_t, bout, x, out, nullptr, nullptr, nullptr);
}

// Round 4
// 208.203 us; speedup vs baseline: 1.2797x; 1.2797x over previous
//
#include <hip/hip_runtime.h>
#include <stdint.h>

typedef __attribute__((ext_vector_type(8))) short short8;
typedef __attribute__((ext_vector_type(4))) float f32x4;
typedef __attribute__((ext_vector_type(16))) float f32x16;
typedef unsigned short u16;
typedef unsigned int u32;

#define NBATCH 8
#define SLEN 1024
#define CDIM 512
#define NHEADS 8
#define HDIM 64
#define MROWS (NBATCH*SLEN)
#define NQKV (NHEADS*3*HDIM)   // 1536
#define QK_SCALE 0.35355339059327373f  // 64^-0.25

__device__ inline u16 f2bf(float f){
  union{float f; uint32_t i;} v; v.f=f;
  uint32_t r = v.i + 0x7fffu + ((v.i>>16)&1u);
  return (u16)(r>>16);
}

// pack two f32 -> bf16x2 word (lo = a, hi = b) via HW cvt_pk (T12 recipe)
__device__ inline u32 pk2(float a, float b){
  u32 r;
  asm("v_cvt_pk_bf16_f32 %0, %1, %2" : "=v"(r) : "v"(a), "v"(b));
  return r;
}

// ---------------- weight prep: cast + transpose to (N, K) bf16 ----------------
__global__ void prep_wqkv(const float* __restrict__ w, u16* __restrict__ wt){
  int idx = blockIdx.x*256 + threadIdx.x;   // over 1536*512
  int n = idx >> 9, k2 = idx & 511;
  wt[idx] = f2bf(w[(size_t)k2*NQKV + n]);
}
__global__ void prep_wout(const float* __restrict__ w, u16* __restrict__ wt){
  int idx = blockIdx.x*256 + threadIdx.x;   // over 512*512
  int n = idx >> 9, k2 = idx & 511;
  wt[idx] = f2bf(w[(size_t)k2*CDIM + n]);
}

// ---------------- groupnorm stats: one block per (b,g) ----------------
__global__ __launch_bounds__(256) void gn_stats(const float* __restrict__ x, float* __restrict__ stats){
  int bid = blockIdx.x;            // b*32+g
  int b = bid >> 5, g = bid & 31;
  int t = threadIdx.x;
  const float* base = x + (size_t)b*SLEN*CDIM + g*16;
  float s1=0.f, s2=0.f;
  for (int s = t; s < SLEN; s += 256){
    const float4* p = (const float4*)(base + (size_t)s*CDIM);
    #pragma unroll
    for (int j=0;j<4;++j){
      float4 v = p[j];
      s1 += v.x+v.y+v.z+v.w;
      s2 += v.x*v.x + v.y*v.y + v.z*v.z + v.w*v.w;
    }
  }
  #pragma unroll
  for (int m=1;m<64;m<<=1){ s1 += __shfl_xor(s1,m); s2 += __shfl_xor(s2,m); }
  __shared__ float red[8];
  int wid = t>>6;
  if ((t&63)==0){ red[wid*2]=s1; red[wid*2+1]=s2; }
  __syncthreads();
  if (t==0){
    float a=0,c=0;
    #pragma unroll
    for (int w2=0;w2<4;++w2){ a+=red[w2*2]; c+=red[w2*2+1]; }
    float mean = a*(1.f/16384.f);
    float var  = c*(1.f/16384.f) - mean*mean;
    stats[bid*2]   = mean;
    stats[bid*2+1] = rsqrtf(var + 1e-5f);
  }
}

// ---------------- normalize + cast to bf16 ----------------
__global__ __launch_bounds__(256) void norm_cast(const float* __restrict__ x, const float* __restrict__ stats,
                        const float* __restrict__ scale, const float* __restrict__ bias,
                        u16* __restrict__ xn){
  int idx = blockIdx.x*256 + threadIdx.x;   // over 8192*32 (one 16-ch group per thread)
  int m = idx >> 5, g = idx & 31;
  int b = m >> 10;
  float mean = stats[(b*32+g)*2];
  float rstd = stats[(b*32+g)*2+1];
  const float* xp = x + (size_t)m*CDIM + g*16;
  const float* sp = scale + g*16;
  const float* bp = bias + g*16;
  short8 o0, o1;
  #pragma unroll
  for (int j=0;j<16;++j){
    float v = (xp[j]-mean)*rstd*sp[j] + bp[j];
    if (j<8) o0[j] = (short)f2bf(v); else o1[j-8] = (short)f2bf(v);
  }
  short8* dst = (short8*)(xn + (size_t)m*CDIM + g*16);
  dst[0]=o0; dst[1]=o1;
}

// ---------------- GEMM: C = A(MxK) * Bt(NxK)^T, bf16 in, fp32 acc ----------------
#define BM 128
#define BN 128
#define BK 64

template<int EPI>
__global__ __launch_bounds__(256, 3) void gemm_bf16(
    const u16* __restrict__ A, const u16* __restrict__ Bt,
    const float* __restrict__ bias, const float* __restrict__ resid,
    float* __restrict__ outF,
    u16* __restrict__ qb, u16* __restrict__ kb, u16* __restrict__ vtb)
{
  const int K = CDIM;
  int t = threadIdx.x;
  int l = t & 63, wid = t >> 6;
  int g = l >> 4, c = l & 15;
  int wr = wid >> 1, wc = wid & 1;
  int m0 = blockIdx.y * BM, n0 = blockIdx.x * BN;

  __shared__ __attribute__((aligned(16))) u16 lsA[BM*BK];
  __shared__ __attribute__((aligned(16))) u16 lsB[BN*BK];
  char* lsAc = (char*)lsA; char* lsBc = (char*)lsB;

  f32x4 acc[4][4];
  #pragma unroll
  for (int i=0;i<4;++i)
    #pragma unroll
    for(int j=0;j<4;++j) acc[i][j] = (f32x4)0.f;

  int srow = t >> 3;      // 0..31
  int ssl  = t & 7;       // 16B slot within 64-col row
  uint4 ra[4], rb[4];
  const int KT = K / BK;  // 8
  #pragma unroll
  for (int i=0;i<4;++i){
    int row = srow + 32*i;
    ra[i] = *(const uint4*)(A  + (size_t)(m0+row)*K + ssl*8);
    rb[i] = *(const uint4*)(Bt + (size_t)(n0+row)*K + ssl*8);
  }
  for (int kt=0; kt<KT; ++kt){
    __syncthreads();
    #pragma unroll
    for (int i=0;i<4;++i){
      int row = srow + 32*i;
      int sw = (ssl ^ (row & 7));
      *(uint4*)(lsAc + row*128 + sw*16) = ra[i];
      *(uint4*)(lsBc + row*128 + sw*16) = rb[i];
    }
    __syncthreads();
    if (kt+1 < KT){
      #pragma unroll
      for (int i=0;i<4;++i){
        int row = srow + 32*i;
        ra[i] = *(const uint4*)(A  + (size_t)(m0+row)*K + (kt+1)*BK + ssl*8);
        rb[i] = *(const uint4*)(Bt + (size_t)(n0+row)*K + (kt+1)*BK + ssl*8);
      }
    }
    #pragma unroll
    for (int kk=0; kk<2; ++kk){
      short8 af[4], bfr[4];
      #pragma unroll
      for (int i=0;i<4;++i){
        int rowA = wr*64 + i*16 + c;
        af[i]  = *(const short8*)(lsAc + rowA*128 + ((kk*4+g) ^ (rowA&7))*16);
        int rowB = wc*64 + i*16 + c;
        bfr[i] = *(const short8*)(lsBc + rowB*128 + ((kk*4+g) ^ (rowB&7))*16);
      }
      #pragma unroll
      for (int i=0;i<4;++i)
        #pragma unroll
        for (int j=0;j<4;++j)
          acc[i][j] = __builtin_amdgcn_mfma_f32_16x16x32_bf16(af[i], bfr[j], acc[i][j], 0,0,0);
    }
  }

  if (EPI == 0){
    int b = m0 >> 10;
    #pragma unroll
    for (int i=0;i<4;++i){
      int grow = m0 + wr*64 + i*16 + g*4;
      #pragma unroll
      for (int j=0;j<4;++j){
        int gcol = n0 + wc*64 + j*16 + c;
        int h = gcol / 192, jj = gcol % 192;
        float bv = bias[gcol];
        #pragma unroll
        for (int r=0;r<4;++r){
          int s = (grow + r) & (SLEN-1);
          float val = acc[i][j][r] + bv;
          if (jj < 64){
            qb[(((size_t)(b*NHEADS+h))*SLEN + s)*HDIM + jj] = f2bf(val*QK_SCALE);
          } else if (jj < 128){
            kb[(((size_t)(b*NHEADS+h))*SLEN + s)*HDIM + (jj-64)] = f2bf(val*QK_SCALE);
          } else {
            vtb[(((size_t)(b*NHEADS+h))*HDIM + (jj-128))*SLEN + s] = f2bf(val);
          }
        }
      }
    }
  } else {
    #pragma unroll
    for (int i=0;i<4;++i){
      int grow = m0 + wr*64 + i*16 + g*4;
      #pragma unroll
      for (int j=0;j<4;++j){
        int gcol = n0 + wc*64 + j*16 + c;
        float bv = bias[gcol];
        #pragma unroll
        for (int r=0;r<4;++r){
          size_t off = (size_t)(grow+r)*CDIM + gcol;
          outF[off] = (acc[i][j][r] + bv + resid[off]);  // SKIP_SCALE == 1.0
        }
      }
    }
  }
}

// ---------------- fused flash attention: swapped-QK^T 32x32 structure (m214 port) ----
// grid: 64 bh * 8 qblocks = 512 blocks; block: 256 thr = 4 INDEPENDENT warps.
// Each warp owns 32 q-rows; iterates 16 kv-tiles of 64 keys.
// S^T = mfma32x32(K, Q): lane owns q = lane&31, holds 32 of 64 keys in-register.
// Softmax: in-lane trees + one shfl_xor(32). P^T -> B-frags via cvt_pk + shfl_xor(32).
// O^T += mfma32x32(V^T, P^T). No LDS, no barriers.
#define PV_KS(PT, QOFF, KS) { \
    u32 A0 = pk2(PT[QOFF+0], PT[QOFF+1]); \
    u32 A1 = pk2(PT[QOFF+2], PT[QOFF+3]); \
    u32 B0 = pk2(PT[QOFF+4], PT[QOFF+5]); \
    u32 B1 = pk2(PT[QOFF+6], PT[QOFF+7]); \
    u32 A0s = __shfl_xor(A0,32), A1s = __shfl_xor(A1,32); \
    u32 B0s = __shfl_xor(B0,32), B1s = __shfl_xor(B1,32); \
    uint4 w; \
    w.x = hi ? B0s : A0;  w.y = hi ? B1s : A1; \
    w.z = hi ? B0  : A0s; w.w = hi ? B1  : A1s; \
    short8 fP; __builtin_memcpy(&fP, &w, 16); \
    o0 = __builtin_amdgcn_mfma_f32_32x32x16_bf16(fV0[KS], fP, o0, 0,0,0); \
    o1 = __builtin_amdgcn_mfma_f32_32x32x16_bf16(fV1[KS], fP, o1, 0,0,0); }

__global__ __launch_bounds__(256, 2) void attn_fused(const u16* __restrict__ qg,
  const u16* __restrict__ kg, const u16* __restrict__ vtg, u16* __restrict__ og)
{
  int bid = blockIdx.x;
  // XCD-contiguous swizzle: each XCD works on 8 consecutive bh (2MB K/V -> L2-fits)
  int nid = (bid & 7)*64 + (bid >> 3);
  int bh = nid >> 3, qi = nid & 7;
  int t = threadIdx.x, l = t & 63, wid = t >> 6;
  int q = l & 31, hi = l >> 5;
  int q0 = qi*128 + wid*32;

  // Q B-frags (held whole kernel): B[k=d][n=q], lane: col q, d = ds*16 + hi*8 + j
  const u16* qrow = qg + ((size_t)bh*SLEN + q0 + q)*HDIM + hi*8;
  short8 fQ[4];
  #pragma unroll
  for (int ds=0; ds<4; ++ds) fQ[ds] = *(const short8*)(qrow + ds*16);

  f32x16 o0, o1;
  #pragma unroll
  for (int r=0;r<16;++r){ o0[r]=0.f; o1[r]=0.f; }
  float mr = -1e30f, lsum = 0.f;

  const u16* kbase = kg  + (size_t)bh*SLEN*HDIM;
  const u16* vbase = vtg + (size_t)bh*HDIM*SLEN;

  for (int kv=0; kv<16; ++kv){
    // K A-frags: A[m=key][k=d], lane: row = key = (lane&31) (+32 for tile1)
    const u16* kp = kbase + (size_t)kv*64*HDIM + hi*8;
    short8 fK0[4], fK1[4];
    #pragma unroll
    for (int ds=0; ds<4; ++ds){
      fK0[ds] = *(const short8*)(kp + (size_t)q*HDIM + ds*16);
      fK1[ds] = *(const short8*)(kp + (size_t)(q+32)*HDIM + ds*16);
    }
    f32x16 p0, p1;
    #pragma unroll
    for (int r=0;r<16;++r){ p0[r]=0.f; p1[r]=0.f; }
    #pragma unroll
    for (int ds=0; ds<4; ++ds){
      p0 = __builtin_amdgcn_mfma_f32_32x32x16_bf16(fK0[ds], fQ[ds], p0, 0,0,0);
      p1 = __builtin_amdgcn_mfma_f32_32x32x16_bf16(fK1[ds], fQ[ds], p1, 0,0,0);
    }
    // V^T A-frags issued early (latency hides under softmax VALU)
    const u16* vp = vbase + kv*64 + hi*8;
    short8 fV0[4], fV1[4];
    #pragma unroll
    for (int ks=0; ks<4; ++ks){
      fV0[ks] = *(const short8*)(vp + (size_t)q*SLEN + ks*16);
      fV1[ks] = *(const short8*)(vp + (size_t)(q+32)*SLEN + ks*16);
    }
    // ---- online softmax: in-lane trees + one cross-half shuffle ----
    float a8[8];
    #pragma unroll
    for (int r=0;r<8;++r)
      a8[r] = fmaxf(fmaxf(p0[r],p0[r+8]), fmaxf(p1[r],p1[r+8]));
    #pragma unroll
    for (int s=4;s>0;s>>=1)
      #pragma unroll
      for (int r=0;r<4;++r) if (r<s) a8[r] = fmaxf(a8[r], a8[r+s]);
    float tmax = fmaxf(a8[0], __shfl_xor(a8[0], 32));
    float mn = fmaxf(mr, tmax);
    float alpha = __expf(mr - mn);
    mr = mn;
    #pragma unroll
    for (int r=0;r<16;++r){ p0[r] = __expf(p0[r]-mn); p1[r] = __expf(p1[r]-mn); }
    float s8[8];
    #pragma unroll
    for (int r=0;r<8;++r) s8[r] = (p0[r]+p0[r+8]) + (p1[r]+p1[r+8]);
    #pragma unroll
    for (int s=4;s>0;s>>=1)
      #pragma unroll
      for (int r=0;r<4;++r) if (r<s) s8[r] += s8[r+s];
    float rs = s8[0] + __shfl_xor(s8[0], 32);
    lsum = lsum*alpha + rs;
    #pragma unroll
    for (int r=0;r<16;++r){ o0[r]*=alpha; o1[r]*=alpha; }
    // ---- P^T -> bf16 B-frags (cvt_pk + half-swap) + PV ----
    PV_KS(p0, 0, 0)
    PV_KS(p0, 8, 1)
    PV_KS(p1, 0, 2)
    PV_KS(p1, 8, 3)
  }

  // epilogue: O^T[d, q] -> og[b, s=q0+q, h*64 + d], d = (reg&3)+8*(reg>>2)+4*hi
  float inv = 1.f / lsum;
  int b = bh >> 3, h = bh & 7;
  u16* obase = og + ((size_t)b*SLEN + q0 + q)*CDIM + h*HDIM;
  #pragma unroll
  for (int pr=0; pr<8; ++pr){
    int d = ((2*pr)&3) + 8*(pr>>1) + 4*hi;
    *(u32*)(obase + d)      = pk2(o0[2*pr]*inv, o0[2*pr+1]*inv);
    *(u32*)(obase + 32 + d) = pk2(o1[2*pr]*inv, o1[2*pr+1]*inv);
  }
}

extern "C" void kernel_launch(void* const* d_in, const int* in_sizes, int n_in,
                              void* d_out, int out_size, void* d_ws, size_t ws_size,
                              hipStream_t stream){
  const float* x      = (const float*)d_in[0];
  const float* nscale = (const float*)d_in[1];
  const float* nbias  = (const float*)d_in[2];
  const float* wqkv   = (const float*)d_in[3];
  const float* bqkv   = (const float*)d_in[4];
  const float* wout   = (const float*)d_in[5];
  const float* bout   = (const float*)d_in[6];
  float* out = (float*)d_out;

  char* ws = (char*)d_ws;
  size_t off = 0;
  auto alloc = [&](size_t bytes){ void* p = ws + off; off += (bytes + 255) & ~255ull; return p; };
  float* stats  = (float*)alloc(256*2*sizeof(float));
  u16* wqkv_t = (u16*)alloc((size_t)NQKV*CDIM*2);
  u16* wout_t = (u16*)alloc((size_t)CDIM*CDIM*2);
  u16* xn     = (u16*)alloc((size_t)MROWS*CDIM*2);
  u16* qb     = (u16*)alloc((size_t)MROWS*CDIM*2);
  u16* kb     = (u16*)alloc((size_t)MROWS*CDIM*2);
  u16* vtb    = (u16*)alloc((size_t)MROWS*CDIM*2);
  u16* ob     = (u16*)alloc((size_t)MROWS*CDIM*2);

  prep_wqkv<<<dim3((NQKV*CDIM)/256), dim3(256), 0, stream>>>(wqkv, wqkv_t);
  prep_wout<<<dim3((CDIM*CDIM)/256), dim3(256), 0, stream>>>(wout, wout_t);
  gn_stats <<<dim3(256), dim3(256), 0, stream>>>(x, stats);
  norm_cast<<<dim3((MROWS*32)/256), dim3(256), 0, stream>>>(x, stats, nscale, nbias, xn);
  gemm_bf16<0><<<dim3(NQKV/BN, MROWS/BM), dim3(256), 0, stream>>>(xn, wqkv_t, bqkv, nullptr, nullptr, qb, kb, vtb);
  attn_fused<<<dim3(512), dim3(256), 0, stream>>>(qb, kb, vtb, ob);
  gemm_bf16<1><<<dim3(CDIM/BN, MROWS/BM), dim3(256), 0, stream>>>(ob, wout_t, bout, x, out, nullptr, nullptr, nullptr);
}

// Round 5
// 200.626 us; speedup vs baseline: 1.3281x; 1.0378x over previous
//
#include <hip/hip_runtime.h>
#include <stdint.h>

typedef __attribute__((ext_vector_type(8))) short short8;
typedef __attribute__((ext_vector_type(4))) float f32x4;
typedef __attribute__((ext_vector_type(16))) float f32x16;
typedef unsigned short u16;
typedef unsigned int u32;

#define NBATCH 8
#define SLEN 1024
#define CDIM 512
#define NHEADS 8
#define HDIM 64
#define MROWS (NBATCH*SLEN)
#define NQKV (NHEADS*3*HDIM)   // 1536
#define QK_SCALE 0.35355339059327373f  // 64^-0.25

__device__ inline u16 f2bf(float f){
  union{float f; uint32_t i;} v; v.f=f;
  uint32_t r = v.i + 0x7fffu + ((v.i>>16)&1u);
  return (u16)(r>>16);
}

// pack two f32 -> bf16x2 word (lo = a, hi = b) via HW cvt_pk (T12 recipe)
__device__ inline u32 pk2(float a, float b){
  u32 r;
  asm("v_cvt_pk_bf16_f32 %0, %1, %2" : "=v"(r) : "v"(a), "v"(b));
  return r;
}

// ---------------- weight prep: cast + transpose to (N, K) bf16 ----------------
__global__ void prep_wqkv(const float* __restrict__ w, u16* __restrict__ wt){
  int idx = blockIdx.x*256 + threadIdx.x;   // over 1536*512
  int n = idx >> 9, k2 = idx & 511;
  wt[idx] = f2bf(w[(size_t)k2*NQKV + n]);
}
__global__ void prep_wout(const float* __restrict__ w, u16* __restrict__ wt){
  int idx = blockIdx.x*256 + threadIdx.x;   // over 512*512
  int n = idx >> 9, k2 = idx & 511;
  wt[idx] = f2bf(w[(size_t)k2*CDIM + n]);
}

// ---------------- groupnorm stats: one block per (b,g) ----------------
__global__ __launch_bounds__(256) void gn_stats(const float* __restrict__ x, float* __restrict__ stats){
  int bid = blockIdx.x;            // b*32+g
  int b = bid >> 5, g = bid & 31;
  int t = threadIdx.x;
  const float* base = x + (size_t)b*SLEN*CDIM + g*16;
  float s1=0.f, s2=0.f;
  for (int s = t; s < SLEN; s += 256){
    const float4* p = (const float4*)(base + (size_t)s*CDIM);
    #pragma unroll
    for (int j=0;j<4;++j){
      float4 v = p[j];
      s1 += v.x+v.y+v.z+v.w;
      s2 += v.x*v.x + v.y*v.y + v.z*v.z + v.w*v.w;
    }
  }
  #pragma unroll
  for (int m=1;m<64;m<<=1){ s1 += __shfl_xor(s1,m); s2 += __shfl_xor(s2,m); }
  __shared__ float red[8];
  int wid = t>>6;
  if ((t&63)==0){ red[wid*2]=s1; red[wid*2+1]=s2; }
  __syncthreads();
  if (t==0){
    float a=0,c=0;
    #pragma unroll
    for (int w2=0;w2<4;++w2){ a+=red[w2*2]; c+=red[w2*2+1]; }
    float mean = a*(1.f/16384.f);
    float var  = c*(1.f/16384.f) - mean*mean;
    stats[bid*2]   = mean;
    stats[bid*2+1] = rsqrtf(var + 1e-5f);
  }
}

// ---------------- normalize + cast to bf16 ----------------
__global__ __launch_bounds__(256) void norm_cast(const float* __restrict__ x, const float* __restrict__ stats,
                        const float* __restrict__ scale, const float* __restrict__ bias,
                        u16* __restrict__ xn){
  int idx = blockIdx.x*256 + threadIdx.x;   // over 8192*32 (one 16-ch group per thread)
  int m = idx >> 5, g = idx & 31;
  int b = m >> 10;
  float mean = stats[(b*32+g)*2];
  float rstd = stats[(b*32+g)*2+1];
  const float* xp = x + (size_t)m*CDIM + g*16;
  const float* sp = scale + g*16;
  const float* bp = bias + g*16;
  short8 o0, o1;
  #pragma unroll
  for (int j=0;j<16;++j){
    float v = (xp[j]-mean)*rstd*sp[j] + bp[j];
    if (j<8) o0[j] = (short)f2bf(v); else o1[j-8] = (short)f2bf(v);
  }
  short8* dst = (short8*)(xn + (size_t)m*CDIM + g*16);
  dst[0]=o0; dst[1]=o1;
}

// ---------------- GEMM: C = A(MxK) * Bt(NxK)^T, bf16 in, fp32 acc ----------------
// 1-D grid with bijective XCD swizzle; NT = N/128 tiles.
// EPI=0: QKV epilogue (q/k direct coalesced; V via LDS-transpose -> contiguous 16B stores)
// EPI=1: out-proj epilogue (+bias+resid, fp32 out)
#define BM 128
#define BN 128
#define BK 64

template<int EPI, int NT>
__global__ __launch_bounds__(256, 3) void gemm_bf16(
    const u16* __restrict__ A, const u16* __restrict__ Bt,
    const float* __restrict__ bias, const float* __restrict__ resid,
    float* __restrict__ outF,
    u16* __restrict__ qb, u16* __restrict__ kb, u16* __restrict__ vtb)
{
  const int K = CDIM;
  int t = threadIdx.x;
  int l = t & 63, wid = t >> 6;
  int g = l >> 4, c = l & 15;
  int wr = wid >> 1, wc = wid & 1;
  // bijective XCD swizzle (nwg % 8 == 0): each XCD gets contiguous M-chunk
  int nwg = gridDim.x;
  int cpx = nwg >> 3;
  int orig = blockIdx.x;
  int swz = (orig & 7)*cpx + (orig >> 3);
  int m0 = (swz / NT) * BM, n0 = (swz % NT) * BN;

  __shared__ __attribute__((aligned(16))) u16 lsA[BM*BK];
  __shared__ __attribute__((aligned(16))) u16 lsB[BN*BK];
  char* lsAc = (char*)lsA; char* lsBc = (char*)lsB;

  f32x4 acc[4][4];
  #pragma unroll
  for (int i=0;i<4;++i)
    #pragma unroll
    for(int j=0;j<4;++j) acc[i][j] = (f32x4)0.f;

  int srow = t >> 3;      // 0..31
  int ssl  = t & 7;       // 16B slot within 64-col row
  uint4 ra[4], rb[4];
  const int KT = K / BK;  // 8
  #pragma unroll
  for (int i=0;i<4;++i){
    int row = srow + 32*i;
    ra[i] = *(const uint4*)(A  + (size_t)(m0+row)*K + ssl*8);
    rb[i] = *(const uint4*)(Bt + (size_t)(n0+row)*K + ssl*8);
  }
  for (int kt=0; kt<KT; ++kt){
    __syncthreads();
    #pragma unroll
    for (int i=0;i<4;++i){
      int row = srow + 32*i;
      int sw = (ssl ^ (row & 7));
      *(uint4*)(lsAc + row*128 + sw*16) = ra[i];
      *(uint4*)(lsBc + row*128 + sw*16) = rb[i];
    }
    __syncthreads();
    if (kt+1 < KT){
      #pragma unroll
      for (int i=0;i<4;++i){
        int row = srow + 32*i;
        ra[i] = *(const uint4*)(A  + (size_t)(m0+row)*K + (kt+1)*BK + ssl*8);
        rb[i] = *(const uint4*)(Bt + (size_t)(n0+row)*K + (kt+1)*BK + ssl*8);
      }
    }
    #pragma unroll
    for (int kk=0; kk<2; ++kk){
      short8 af[4], bfr[4];
      #pragma unroll
      for (int i=0;i<4;++i){
        int rowA = wr*64 + i*16 + c;
        af[i]  = *(const short8*)(lsAc + rowA*128 + ((kk*4+g) ^ (rowA&7))*16);
        int rowB = wc*64 + i*16 + c;
        bfr[i] = *(const short8*)(lsBc + rowB*128 + ((kk*4+g) ^ (rowB&7))*16);
      }
      #pragma unroll
      for (int i=0;i<4;++i)
        #pragma unroll
        for (int j=0;j<4;++j)
          acc[i][j] = __builtin_amdgcn_mfma_f32_16x16x32_bf16(af[i], bfr[j], acc[i][j], 0,0,0);
    }
  }

  if (EPI == 0){
    int b = m0 >> 10;
    __syncthreads();            // done reading lsA/lsB; reuse as V-transpose buffer
    u16* lsV = (u16*)lsA;       // [64][136] padded (stride 136 u16 = 272 B)
    #pragma unroll
    for (int i=0;i<4;++i){
      int rl0 = wr*64 + i*16 + g*4;
      int grow = m0 + rl0;
      #pragma unroll
      for (int j=0;j<4;++j){
        int gcol = n0 + wc*64 + j*16 + c;
        int h = gcol / 192, jj = gcol % 192;
        float bv = bias[gcol];
        #pragma unroll
        for (int r=0;r<4;++r){
          int s = (grow + r) & (SLEN-1);
          float val = acc[i][j][r] + bv;
          if (jj < 64){
            qb[(((size_t)(b*NHEADS+h))*SLEN + s)*HDIM + jj] = f2bf(val*QK_SCALE);
          } else if (jj < 128){
            kb[(((size_t)(b*NHEADS+h))*SLEN + s)*HDIM + (jj-64)] = f2bf(val*QK_SCALE);
          } else {
            lsV[(jj-128)*136 + rl0 + r] = f2bf(val);
          }
        }
      }
    }
    __syncthreads();
    int blk3 = (n0 >> 7) % 3;   // 0: no v-cols; 1: v at local 0-63; 2: v at local 64-127
    if (blk3 != 0){
      int hv = (n0 + ((blk3==1)?0:64)) / 192;
      int s0 = m0 & (SLEN-1);
      size_t vbase = ((size_t)(b*NHEADS+hv))*HDIM*SLEN;
      #pragma unroll
      for (int cc=0; cc<4; ++cc){
        int chunk = cc*256 + t;        // 1024 chunks of 8 u16
        int d = chunk >> 4, so = (chunk & 15)*8;
        uint4 vv = *(const uint4*)(lsV + d*136 + so);
        *(uint4*)(vtb + vbase + (size_t)d*SLEN + s0 + so) = vv;
      }
    }
  } else {
    #pragma unroll
    for (int i=0;i<4;++i){
      int grow = m0 + wr*64 + i*16 + g*4;
      #pragma unroll
      for (int j=0;j<4;++j){
        int gcol = n0 + wc*64 + j*16 + c;
        float bv = bias[gcol];
        #pragma unroll
        for (int r=0;r<4;++r){
          size_t off = (size_t)(grow+r)*CDIM + gcol;
          outF[off] = (acc[i][j][r] + bv + resid[off]);  // SKIP_SCALE == 1.0
        }
      }
    }
  }
}

// ---------------- fused flash attention: swapped-QK^T 32x32 structure (m214 port) ----
// grid: 64 bh * 8 qblocks = 512 blocks; block: 256 thr = 4 INDEPENDENT warps.
// Each warp owns 32 q-rows; iterates 16 kv-tiles of 64 keys.
// S^T = mfma32x32(K, Q): lane owns q = lane&31, holds 32 of 64 keys in-register.
// Softmax: in-lane trees + one shfl_xor(32). P^T -> B-frags via cvt_pk + shfl_xor(32).
// O^T += mfma32x32(V^T, P^T). No LDS, no barriers.
#define PV_KS(PT, QOFF, KS) { \
    u32 A0 = pk2(PT[QOFF+0], PT[QOFF+1]); \
    u32 A1 = pk2(PT[QOFF+2], PT[QOFF+3]); \
    u32 B0 = pk2(PT[QOFF+4], PT[QOFF+5]); \
    u32 B1 = pk2(PT[QOFF+6], PT[QOFF+7]); \
    u32 A0s = __shfl_xor(A0,32), A1s = __shfl_xor(A1,32); \
    u32 B0s = __shfl_xor(B0,32), B1s = __shfl_xor(B1,32); \
    uint4 w; \
    w.x = hi ? B0s : A0;  w.y = hi ? B1s : A1; \
    w.z = hi ? B0  : A0s; w.w = hi ? B1  : A1s; \
    short8 fP; __builtin_memcpy(&fP, &w, 16); \
    o0 = __builtin_amdgcn_mfma_f32_32x32x16_bf16(fV0[KS], fP, o0, 0,0,0); \
    o1 = __builtin_amdgcn_mfma_f32_32x32x16_bf16(fV1[KS], fP, o1, 0,0,0); }

__global__ __launch_bounds__(256, 2) void attn_fused(const u16* __restrict__ qg,
  const u16* __restrict__ kg, const u16* __restrict__ vtg, u16* __restrict__ og)
{
  int bid = blockIdx.x;
  // XCD-contiguous swizzle: each XCD works on 8 consecutive bh (2MB K/V -> L2-fits)
  int nid = (bid & 7)*64 + (bid >> 3);
  int bh = nid >> 3, qi = nid & 7;
  int t = threadIdx.x, l = t & 63, wid = t >> 6;
  int q = l & 31, hi = l >> 5;
  int q0 = qi*128 + wid*32;

  // Q B-frags (held whole kernel): B[k=d][n=q], lane: col q, d = ds*16 + hi*8 + j
  const u16* qrow = qg + ((size_t)bh*SLEN + q0 + q)*HDIM + hi*8;
  short8 fQ[4];
  #pragma unroll
  for (int ds=0; ds<4; ++ds) fQ[ds] = *(const short8*)(qrow + ds*16);

  f32x16 o0, o1;
  #pragma unroll
  for (int r=0;r<16;++r){ o0[r]=0.f; o1[r]=0.f; }
  float mr = -1e30f, lsum = 0.f;

  const u16* kbase = kg  + (size_t)bh*SLEN*HDIM;
  const u16* vbase = vtg + (size_t)bh*HDIM*SLEN;

  for (int kv=0; kv<16; ++kv){
    // K A-frags: A[m=key][k=d], lane: row = key = (lane&31) (+32 for tile1)
    const u16* kp = kbase + (size_t)kv*64*HDIM + hi*8;
    short8 fK0[4], fK1[4];
    #pragma unroll
    for (int ds=0; ds<4; ++ds){
      fK0[ds] = *(const short8*)(kp + (size_t)q*HDIM + ds*16);
      fK1[ds] = *(const short8*)(kp + (size_t)(q+32)*HDIM + ds*16);
    }
    f32x16 p0, p1;
    #pragma unroll
    for (int r=0;r<16;++r){ p0[r]=0.f; p1[r]=0.f; }
    #pragma unroll
    for (int ds=0; ds<4; ++ds){
      p0 = __builtin_amdgcn_mfma_f32_32x32x16_bf16(fK0[ds], fQ[ds], p0, 0,0,0);
      p1 = __builtin_amdgcn_mfma_f32_32x32x16_bf16(fK1[ds], fQ[ds], p1, 0,0,0);
    }
    // V^T A-frags issued early (latency hides under softmax VALU)
    const u16* vp = vbase + kv*64 + hi*8;
    short8 fV0[4], fV1[4];
    #pragma unroll
    for (int ks=0; ks<4; ++ks){
      fV0[ks] = *(const short8*)(vp + (size_t)q*SLEN + ks*16);
      fV1[ks] = *(const short8*)(vp + (size_t)(q+32)*SLEN + ks*16);
    }
    // ---- online softmax: in-lane trees + one cross-half shuffle ----
    float a8[8];
    #pragma unroll
    for (int r=0;r<8;++r)
      a8[r] = fmaxf(fmaxf(p0[r],p0[r+8]), fmaxf(p1[r],p1[r+8]));
    #pragma unroll
    for (int s=4;s>0;s>>=1)
      #pragma unroll
      for (int r=0;r<4;++r) if (r<s) a8[r] = fmaxf(a8[r], a8[r+s]);
    float tmax = fmaxf(a8[0], __shfl_xor(a8[0], 32));
    float mn = fmaxf(mr, tmax);
    float alpha = __expf(mr - mn);
    mr = mn;
    #pragma unroll
    for (int r=0;r<16;++r){ p0[r] = __expf(p0[r]-mn); p1[r] = __expf(p1[r]-mn); }
    float s8[8];
    #pragma unroll
    for (int r=0;r<8;++r) s8[r] = (p0[r]+p0[r+8]) + (p1[r]+p1[r+8]);
    #pragma unroll
    for (int s=4;s>0;s>>=1)
      #pragma unroll
      for (int r=0;r<4;++r) if (r<s) s8[r] += s8[r+s];
    float rs = s8[0] + __shfl_xor(s8[0], 32);
    lsum = lsum*alpha + rs;
    #pragma unroll
    for (int r=0;r<16;++r){ o0[r]*=alpha; o1[r]*=alpha; }
    // ---- P^T -> bf16 B-frags (cvt_pk + half-swap) + PV ----
    PV_KS(p0, 0, 0)
    PV_KS(p0, 8, 1)
    PV_KS(p1, 0, 2)
    PV_KS(p1, 8, 3)
  }

  // epilogue: O^T[d, q] -> og[b, s=q0+q, h*64 + d], d = (reg&3)+8*(reg>>2)+4*hi
  float inv = 1.f / lsum;
  int b = bh >> 3, h = bh & 7;
  u16* obase = og + ((size_t)b*SLEN + q0 + q)*CDIM + h*HDIM;
  #pragma unroll
  for (int pr=0; pr<8; ++pr){
    int d = ((2*pr)&3) + 8*(pr>>1) + 4*hi;
    *(u32*)(obase + d)      = pk2(o0[2*pr]*inv, o0[2*pr+1]*inv);
    *(u32*)(obase + 32 + d) = pk2(o1[2*pr]*inv, o1[2*pr+1]*inv);
  }
}

extern "C" void kernel_launch(void* const* d_in, const int* in_sizes, int n_in,
                              void* d_out, int out_size, void* d_ws, size_t ws_size,
                              hipStream_t stream){
  const float* x      = (const float*)d_in[0];
  const float* nscale = (const float*)d_in[1];
  const float* nbias  = (const float*)d_in[2];
  const float* wqkv   = (const float*)d_in[3];
  const float* bqkv   = (const float*)d_in[4];
  const float* wout   = (const float*)d_in[5];
  const float* bout   = (const float*)d_in[6];
  float* out = (float*)d_out;

  char* ws = (char*)d_ws;
  size_t off = 0;
  auto alloc = [&](size_t bytes){ void* p = ws + off; off += (bytes + 255) & ~255ull; return p; };
  float* stats  = (float*)alloc(256*2*sizeof(float));
  u16* wqkv_t = (u16*)alloc((size_t)NQKV*CDIM*2);
  u16* wout_t = (u16*)alloc((size_t)CDIM*CDIM*2);
  u16* xn     = (u16*)alloc((size_t)MROWS*CDIM*2);
  u16* qb     = (u16*)alloc((size_t)MROWS*CDIM*2);
  u16* kb     = (u16*)alloc((size_t)MROWS*CDIM*2);
  u16* vtb    = (u16*)alloc((size_t)MROWS*CDIM*2);
  u16* ob     = (u16*)alloc((size_t)MROWS*CDIM*2);

  prep_wqkv<<<dim3((NQKV*CDIM)/256), dim3(256), 0, stream>>>(wqkv, wqkv_t);
  prep_wout<<<dim3((CDIM*CDIM)/256), dim3(256), 0, stream>>>(wout, wout_t);
  gn_stats <<<dim3(256), dim3(256), 0, stream>>>(x, stats);
  norm_cast<<<dim3((MROWS*32)/256), dim3(256), 0, stream>>>(x, stats, nscale, nbias, xn);
  gemm_bf16<0,12><<<dim3(768), dim3(256), 0, stream>>>(xn, wqkv_t, bqkv, nullptr, nullptr, qb, kb, vtb);
  attn_fused<<<dim3(512), dim3(256), 0, stream>>>(qb, kb, vtb, ob);
  gemm_bf16<1,4><<<dim3(256), dim3(256), 0, stream>>>(ob, wout_t, bout, x, out, nullptr, nullptr, nullptr);
}

// Round 6
// 198.459 us; speedup vs baseline: 1.3426x; 1.0109x over previous
//
#include <hip/hip_runtime.h>
#include <stdint.h>

typedef __attribute__((ext_vector_type(8))) short short8;
typedef __attribute__((ext_vector_type(4))) float f32x4;
typedef __attribute__((ext_vector_type(16))) float f32x16;
typedef unsigned short u16;
typedef unsigned int u32;

#define NBATCH 8
#define SLEN 1024
#define CDIM 512
#define NHEADS 8
#define HDIM 64
#define MROWS (NBATCH*SLEN)
#define NQKV (NHEADS*3*HDIM)   // 1536
#define QK_SCALE 0.35355339059327373f  // 64^-0.25

__device__ inline u16 f2bf(float f){
  union{float f; uint32_t i;} v; v.f=f;
  uint32_t r = v.i + 0x7fffu + ((v.i>>16)&1u);
  return (u16)(r>>16);
}

// pack two f32 -> bf16x2 word (lo = a, hi = b) via HW cvt_pk (T12 recipe)
__device__ inline u32 pk2(float a, float b){
  u32 r;
  asm("v_cvt_pk_bf16_f32 %0, %1, %2" : "=v"(r) : "v"(a), "v"(b));
  return r;
}

// ---------------- weight prep: cast + transpose to (N, K) bf16 ----------------
__global__ void prep_wqkv(const float* __restrict__ w, u16* __restrict__ wt){
  int idx = blockIdx.x*256 + threadIdx.x;   // over 1536*512
  int n = idx >> 9, k2 = idx & 511;
  wt[idx] = f2bf(w[(size_t)k2*NQKV + n]);
}
__global__ void prep_wout(const float* __restrict__ w, u16* __restrict__ wt){
  int idx = blockIdx.x*256 + threadIdx.x;   // over 512*512
  int n = idx >> 9, k2 = idx & 511;
  wt[idx] = f2bf(w[(size_t)k2*CDIM + n]);
}

// ---------------- groupnorm stats: one block per (b,g) ----------------
__global__ __launch_bounds__(256) void gn_stats(const float* __restrict__ x, float* __restrict__ stats){
  int bid = blockIdx.x;            // b*32+g
  int b = bid >> 5, g = bid & 31;
  int t = threadIdx.x;
  const float* base = x + (size_t)b*SLEN*CDIM + g*16;
  float s1=0.f, s2=0.f;
  for (int s = t; s < SLEN; s += 256){
    const float4* p = (const float4*)(base + (size_t)s*CDIM);
    #pragma unroll
    for (int j=0;j<4;++j){
      float4 v = p[j];
      s1 += v.x+v.y+v.z+v.w;
      s2 += v.x*v.x + v.y*v.y + v.z*v.z + v.w*v.w;
    }
  }
  #pragma unroll
  for (int m=1;m<64;m<<=1){ s1 += __shfl_xor(s1,m); s2 += __shfl_xor(s2,m); }
  __shared__ float red[8];
  int wid = t>>6;
  if ((t&63)==0){ red[wid*2]=s1; red[wid*2+1]=s2; }
  __syncthreads();
  if (t==0){
    float a=0,c=0;
    #pragma unroll
    for (int w2=0;w2<4;++w2){ a+=red[w2*2]; c+=red[w2*2+1]; }
    float mean = a*(1.f/16384.f);
    float var  = c*(1.f/16384.f) - mean*mean;
    stats[bid*2]   = mean;
    stats[bid*2+1] = rsqrtf(var + 1e-5f);
  }
}

// ---------------- normalize + cast to bf16 ----------------
__global__ __launch_bounds__(256) void norm_cast(const float* __restrict__ x, const float* __restrict__ stats,
                        const float* __restrict__ scale, const float* __restrict__ bias,
                        u16* __restrict__ xn){
  int idx = blockIdx.x*256 + threadIdx.x;   // over 8192*32 (one 16-ch group per thread)
  int m = idx >> 5, g = idx & 31;
  int b = m >> 10;
  float mean = stats[(b*32+g)*2];
  float rstd = stats[(b*32+g)*2+1];
  const float* xp = x + (size_t)m*CDIM + g*16;
  const float* sp = scale + g*16;
  const float* bp = bias + g*16;
  short8 o0, o1;
  #pragma unroll
  for (int j=0;j<16;++j){
    float v = (xp[j]-mean)*rstd*sp[j] + bp[j];
    if (j<8) o0[j] = (short)f2bf(v); else o1[j-8] = (short)f2bf(v);
  }
  short8* dst = (short8*)(xn + (size_t)m*CDIM + g*16);
  dst[0]=o0; dst[1]=o1;
}

// ---------------- GEMM: C = A(MxK) * Bt(NxK)^T, bf16 in, fp32 acc ----------------
// 1-D grid with bijective XCD swizzle; NT = N/128 tiles.
// EPI=0: QKV epilogue — full C tile staged in LDS, ALL outputs written as
//        16B-per-lane coalesced chunks (q/k direct; V via padded LDS transpose).
// EPI=1: out-proj epilogue (+bias+resid, fp32 out; already full-line stores)
#define BM 128
#define BN 128
#define BK 64

template<int EPI, int NT>
__global__ __launch_bounds__(256, 3) void gemm_bf16(
    const u16* __restrict__ A, const u16* __restrict__ Bt,
    const float* __restrict__ bias, const float* __restrict__ resid,
    float* __restrict__ outF,
    u16* __restrict__ qb, u16* __restrict__ kb, u16* __restrict__ vtb)
{
  const int K = CDIM;
  int t = threadIdx.x;
  int l = t & 63, wid = t >> 6;
  int g = l >> 4, c = l & 15;
  int wr = wid >> 1, wc = wid & 1;
  // bijective XCD swizzle (nwg % 8 == 0): each XCD gets contiguous M-chunk
  int nwg = gridDim.x;
  int cpx = nwg >> 3;
  int orig = blockIdx.x;
  int swz = (orig & 7)*cpx + (orig >> 3);
  int m0 = (swz / NT) * BM, n0 = (swz % NT) * BN;

  __shared__ __attribute__((aligned(16))) u16 ls[16384];   // 32 KB: lsA[8192] + lsB[8192]
  char* lsAc = (char*)ls; char* lsBc = (char*)(ls + 8192);

  f32x4 acc[4][4];
  #pragma unroll
  for (int i=0;i<4;++i)
    #pragma unroll
    for(int j=0;j<4;++j) acc[i][j] = (f32x4)0.f;

  int srow = t >> 3;      // 0..31
  int ssl  = t & 7;       // 16B slot within 64-col row
  uint4 ra[4], rb[4];
  const int KT = K / BK;  // 8
  #pragma unroll
  for (int i=0;i<4;++i){
    int row = srow + 32*i;
    ra[i] = *(const uint4*)(A  + (size_t)(m0+row)*K + ssl*8);
    rb[i] = *(const uint4*)(Bt + (size_t)(n0+row)*K + ssl*8);
  }
  for (int kt=0; kt<KT; ++kt){
    __syncthreads();
    #pragma unroll
    for (int i=0;i<4;++i){
      int row = srow + 32*i;
      int sw = (ssl ^ (row & 7));
      *(uint4*)(lsAc + row*128 + sw*16) = ra[i];
      *(uint4*)(lsBc + row*128 + sw*16) = rb[i];
    }
    __syncthreads();
    if (kt+1 < KT){
      #pragma unroll
      for (int i=0;i<4;++i){
        int row = srow + 32*i;
        ra[i] = *(const uint4*)(A  + (size_t)(m0+row)*K + (kt+1)*BK + ssl*8);
        rb[i] = *(const uint4*)(Bt + (size_t)(n0+row)*K + (kt+1)*BK + ssl*8);
      }
    }
    #pragma unroll
    for (int kk=0; kk<2; ++kk){
      short8 af[4], bfr[4];
      #pragma unroll
      for (int i=0;i<4;++i){
        int rowA = wr*64 + i*16 + c;
        af[i]  = *(const short8*)(lsAc + rowA*128 + ((kk*4+g) ^ (rowA&7))*16);
        int rowB = wc*64 + i*16 + c;
        bfr[i] = *(const short8*)(lsBc + rowB*128 + ((kk*4+g) ^ (rowB&7))*16);
      }
      #pragma unroll
      for (int i=0;i<4;++i)
        #pragma unroll
        for (int j=0;j<4;++j)
          acc[i][j] = __builtin_amdgcn_mfma_f32_16x16x32_bf16(af[i], bfr[j], acc[i][j], 0,0,0);
    }
  }

  if (EPI == 0){
    int b = m0 >> 10, s0 = m0 & (SLEN-1);
    // ---- pass 1: stage full C tile (scaled+biased bf16) into lsC[128][128] ----
    __syncthreads();            // done reading lsA/lsB
    u16* lsC = ls;
    #pragma unroll
    for (int i=0;i<4;++i){
      int rl0 = wr*64 + i*16 + g*4;
      #pragma unroll
      for (int j=0;j<4;++j){
        int cl = wc*64 + j*16 + c;
        int gcol = n0 + cl;
        int jj = gcol % 192;
        float sc_ = (jj < 128) ? QK_SCALE : 1.0f;
        float bv = bias[gcol];
        #pragma unroll
        for (int r=0;r<4;++r)
          lsC[(rl0+r)*128 + cl] = f2bf((acc[i][j][r] + bv)*sc_);
      }
    }
    __syncthreads();
    // ---- pass 2: coalesced q/k stores, 16B per lane (2048 chunks of 8 u16) ----
    #pragma unroll
    for (int cc=0; cc<8; ++cc){
      int ch = cc*256 + t;
      int rl = ch >> 4, slot = ch & 15;
      int cl = slot*8;
      int gcol = n0 + cl;
      int h = gcol / 192, jj = gcol % 192;
      int s = s0 + rl;
      uint4 vv = *(const uint4*)(lsC + rl*128 + cl);
      size_t rowb = ((size_t)(b*NHEADS+h))*SLEN + s;
      if (jj < 64)       *(uint4*)(qb + rowb*HDIM + jj)      = vv;
      else if (jj < 128) *(uint4*)(kb + rowb*HDIM + (jj-64)) = vv;
    }
    // ---- pass 3: V via padded LDS transpose -> coalesced 16B chunks along s ----
    int blk3 = (n0 >> 7) % 3;   // 0: no v-cols; 1: v at local 0-63; 2: v at local 64-127
    if (blk3 != 0){
      __syncthreads();          // pass-2 reads of lsC done; reuse as lsV
      u16* lsV = ls;            // [64][136] padded (17390 B < 32 KB)
      #pragma unroll
      for (int i=0;i<4;++i){
        int rl0 = wr*64 + i*16 + g*4;
        #pragma unroll
        for (int j=0;j<4;++j){
          int cl = wc*64 + j*16 + c;
          int jj = (n0 + cl) % 192;
          if (jj >= 128){
            #pragma unroll
            for (int r=0;r<4;++r)
              lsV[(jj-128)*136 + rl0 + r] = f2bf(acc[i][j][r] + bias[n0+cl]);
          }
        }
      }
      __syncthreads();
      int hv = (n0 + ((blk3==1)?0:64)) / 192;
      size_t vbase = ((size_t)(b*NHEADS+hv))*HDIM*SLEN;
      #pragma unroll
      for (int cc=0; cc<4; ++cc){
        int chunk = cc*256 + t;        // 1024 chunks of 8 u16
        int d = chunk >> 4, so = (chunk & 15)*8;
        uint4 vv = *(const uint4*)(lsV + d*136 + so);
        *(uint4*)(vtb + vbase + (size_t)d*SLEN + s0 + so) = vv;
      }
    }
  } else {
    #pragma unroll
    for (int i=0;i<4;++i){
      int grow = m0 + wr*64 + i*16 + g*4;
      #pragma unroll
      for (int j=0;j<4;++j){
        int gcol = n0 + wc*64 + j*16 + c;
        float bv = bias[gcol];
        #pragma unroll
        for (int r=0;r<4;++r){
          size_t off = (size_t)(grow+r)*CDIM + gcol;
          outF[off] = (acc[i][j][r] + bv + resid[off]);  // SKIP_SCALE == 1.0
        }
      }
    }
  }
}

// ---------------- fused flash attention: swapped-QK^T 32x32 structure (m214 port) ----
// grid: 64 bh * 8 qblocks = 512 blocks; block: 256 thr = 4 INDEPENDENT warps.
// Each warp owns 32 q-rows; iterates 16 kv-tiles of 64 keys.
// S^T = mfma32x32(K, Q): lane owns q = lane&31, holds 32 of 64 keys in-register.
// Softmax: in-lane trees + one shfl_xor(32). P^T -> B-frags via cvt_pk + shfl_xor(32).
// O^T += mfma32x32(V^T, P^T). No LDS, no barriers.
#define PV_KS(PT, QOFF, KS) { \
    u32 A0 = pk2(PT[QOFF+0], PT[QOFF+1]); \
    u32 A1 = pk2(PT[QOFF+2], PT[QOFF+3]); \
    u32 B0 = pk2(PT[QOFF+4], PT[QOFF+5]); \
    u32 B1 = pk2(PT[QOFF+6], PT[QOFF+7]); \
    u32 A0s = __shfl_xor(A0,32), A1s = __shfl_xor(A1,32); \
    u32 B0s = __shfl_xor(B0,32), B1s = __shfl_xor(B1,32); \
    uint4 w; \
    w.x = hi ? B0s : A0;  w.y = hi ? B1s : A1; \
    w.z = hi ? B0  : A0s; w.w = hi ? B1  : A1s; \
    short8 fP; __builtin_memcpy(&fP, &w, 16); \
    o0 = __builtin_amdgcn_mfma_f32_32x32x16_bf16(fV0[KS], fP, o0, 0,0,0); \
    o1 = __builtin_amdgcn_mfma_f32_32x32x16_bf16(fV1[KS], fP, o1, 0,0,0); }

__global__ __launch_bounds__(256, 2) void attn_fused(const u16* __restrict__ qg,
  const u16* __restrict__ kg, const u16* __restrict__ vtg, u16* __restrict__ og)
{
  int bid = blockIdx.x;
  // XCD-contiguous swizzle: each XCD works on 8 consecutive bh (2MB K/V -> L2-fits)
  int nid = (bid & 7)*64 + (bid >> 3);
  int bh = nid >> 3, qi = nid & 7;
  int t = threadIdx.x, l = t & 63, wid = t >> 6;
  int q = l & 31, hi = l >> 5;
  int q0 = qi*128 + wid*32;

  // Q B-frags (held whole kernel): B[k=d][n=q], lane: col q, d = ds*16 + hi*8 + j
  const u16* qrow = qg + ((size_t)bh*SLEN + q0 + q)*HDIM + hi*8;
  short8 fQ[4];
  #pragma unroll
  for (int ds=0; ds<4; ++ds) fQ[ds] = *(const short8*)(qrow + ds*16);

  f32x16 o0, o1;
  #pragma unroll
  for (int r=0;r<16;++r){ o0[r]=0.f; o1[r]=0.f; }
  float mr = -1e30f, lsum = 0.f;

  const u16* kbase = kg  + (size_t)bh*SLEN*HDIM;
  const u16* vbase = vtg + (size_t)bh*HDIM*SLEN;

  for (int kv=0; kv<16; ++kv){
    // K A-frags: A[m=key][k=d], lane: row = key = (lane&31) (+32 for tile1)
    const u16* kp = kbase + (size_t)kv*64*HDIM + hi*8;
    short8 fK0[4], fK1[4];
    #pragma unroll
    for (int ds=0; ds<4; ++ds){
      fK0[ds] = *(const short8*)(kp + (size_t)q*HDIM + ds*16);
      fK1[ds] = *(const short8*)(kp + (size_t)(q+32)*HDIM + ds*16);
    }
    f32x16 p0, p1;
    #pragma unroll
    for (int r=0;r<16;++r){ p0[r]=0.f; p1[r]=0.f; }
    #pragma unroll
    for (int ds=0; ds<4; ++ds){
      p0 = __builtin_amdgcn_mfma_f32_32x32x16_bf16(fK0[ds], fQ[ds], p0, 0,0,0);
      p1 = __builtin_amdgcn_mfma_f32_32x32x16_bf16(fK1[ds], fQ[ds], p1, 0,0,0);
    }
    // V^T A-frags issued early (latency hides under softmax VALU)
    const u16* vp = vbase + kv*64 + hi*8;
    short8 fV0[4], fV1[4];
    #pragma unroll
    for (int ks=0; ks<4; ++ks){
      fV0[ks] = *(const short8*)(vp + (size_t)q*SLEN + ks*16);
      fV1[ks] = *(const short8*)(vp + (size_t)(q+32)*SLEN + ks*16);
    }
    // ---- online softmax: in-lane trees + one cross-half shuffle ----
    float a8[8];
    #pragma unroll
    for (int r=0;r<8;++r)
      a8[r] = fmaxf(fmaxf(p0[r],p0[r+8]), fmaxf(p1[r],p1[r+8]));
    #pragma unroll
    for (int s=4;s>0;s>>=1)
      #pragma unroll
      for (int r=0;r<4;++r) if (r<s) a8[r] = fmaxf(a8[r], a8[r+s]);
    float tmax = fmaxf(a8[0], __shfl_xor(a8[0], 32));
    float mn = fmaxf(mr, tmax);
    float alpha = __expf(mr - mn);
    mr = mn;
    #pragma unroll
    for (int r=0;r<16;++r){ p0[r] = __expf(p0[r]-mn); p1[r] = __expf(p1[r]-mn); }
    float s8[8];
    #pragma unroll
    for (int r=0;r<8;++r) s8[r] = (p0[r]+p0[r+8]) + (p1[r]+p1[r+8]);
    #pragma unroll
    for (int s=4;s>0;s>>=1)
      #pragma unroll
      for (int r=0;r<4;++r) if (r<s) s8[r] += s8[r+s];
    float rs = s8[0] + __shfl_xor(s8[0], 32);
    lsum = lsum*alpha + rs;
    #pragma unroll
    for (int r=0;r<16;++r){ o0[r]*=alpha; o1[r]*=alpha; }
    // ---- P^T -> bf16 B-frags (cvt_pk + half-swap) + PV ----
    PV_KS(p0, 0, 0)
    PV_KS(p0, 8, 1)
    PV_KS(p1, 0, 2)
    PV_KS(p1, 8, 3)
  }

  // epilogue: O^T[d, q] -> og[b, s=q0+q, h*64 + d], d = (reg&3)+8*(reg>>2)+4*hi
  float inv = 1.f / lsum;
  int b = bh >> 3, h = bh & 7;
  u16* obase = og + ((size_t)b*SLEN + q0 + q)*CDIM + h*HDIM;
  #pragma unroll
  for (int pr=0; pr<8; ++pr){
    int d = ((2*pr)&3) + 8*(pr>>1) + 4*hi;
    *(u32*)(obase + d)      = pk2(o0[2*pr]*inv, o0[2*pr+1]*inv);
    *(u32*)(obase + 32 + d) = pk2(o1[2*pr]*inv, o1[2*pr+1]*inv);
  }
}

extern "C" void kernel_launch(void* const* d_in, const int* in_sizes, int n_in,
                              void* d_out, int out_size, void* d_ws, size_t ws_size,
                              hipStream_t stream){
  const float* x      = (const float*)d_in[0];
  const float* nscale = (const float*)d_in[1];
  const float* nbias  = (const float*)d_in[2];
  const float* wqkv   = (const float*)d_in[3];
  const float* bqkv   = (const float*)d_in[4];
  const float* wout   = (const float*)d_in[5];
  const float* bout   = (const float*)d_in[6];
  float* out = (float*)d_out;

  char* ws = (char*)d_ws;
  size_t off = 0;
  auto alloc = [&](size_t bytes){ void* p = ws + off; off += (bytes + 255) & ~255ull; return p; };
  float* stats  = (float*)alloc(256*2*sizeof(float));
  u16* wqkv_t = (u16*)alloc((size_t)NQKV*CDIM*2);
  u16* wout_t = (u16*)alloc((size_t)CDIM*CDIM*2);
  u16* xn     = (u16*)alloc((size_t)MROWS*CDIM*2);
  u16* qb     = (u16*)alloc((size_t)MROWS*CDIM*2);
  u16* kb     = (u16*)alloc((size_t)MROWS*CDIM*2);
  u16* vtb    = (u16*)alloc((size_t)MROWS*CDIM*2);
  u16* ob     = (u16*)alloc((size_t)MROWS*CDIM*2);

  prep_wqkv<<<dim3((NQKV*CDIM)/256), dim3(256), 0, stream>>>(wqkv, wqkv_t);
  prep_wout<<<dim3((CDIM*CDIM)/256), dim3(256), 0, stream>>>(wout, wout_t);
  gn_stats <<<dim3(256), dim3(256), 0, stream>>>(x, stats);
  norm_cast<<<dim3((MROWS*32)/256), dim3(256), 0, stream>>>(x, stats, nscale, nbias, xn);
  gemm_bf16<0,12><<<dim3(768), dim3(256), 0, stream>>>(xn, wqkv_t, bqkv, nullptr, nullptr, qb, kb, vtb);
  attn_fused<<<dim3(512), dim3(256), 0, stream>>>(qb, kb, vtb, ob);
  gemm_bf16<1,4><<<dim3(256), dim3(256), 0, stream>>>(ob, wout_t, bout, x, out, nullptr, nullptr, nullptr);
}

// Round 7
// 125.880 us; speedup vs baseline: 2.1166x; 1.5766x over previous
//
#include <hip/hip_runtime.h>
#include <stdint.h>

typedef __attribute__((ext_vector_type(8))) short short8;
typedef __attribute__((ext_vector_type(4))) float f32x4;
typedef __attribute__((ext_vector_type(16))) float f32x16;
typedef __attribute__((ext_vector_type(4))) unsigned int u32x4;
typedef unsigned short u16;
typedef unsigned int u32;

#define NBATCH 8
#define SLEN 1024
#define CDIM 512
#define NHEADS 8
#define HDIM 64
#define MROWS (NBATCH*SLEN)
#define NQKV (NHEADS*3*HDIM)   // 1536
#define QK_SCALE 0.35355339059327373f  // 64^-0.25

__device__ inline u16 f2bf(float f){
  union{float f; uint32_t i;} v; v.f=f;
  uint32_t r = v.i + 0x7fffu + ((v.i>>16)&1u);
  return (u16)(r>>16);
}

// pack two f32 -> bf16x2 word (lo = a, hi = b) via HW cvt_pk (T12 recipe)
__device__ inline u32 pk2(float a, float b){
  u32 r;
  asm("v_cvt_pk_bf16_f32 %0, %1, %2" : "=v"(r) : "v"(a), "v"(b));
  return r;
}

// async global->LDS, 16B per lane; LDS dest = wave-uniform base + lane*16
__device__ __forceinline__ void gld16(const u16* g, u16* l){
  __builtin_amdgcn_global_load_lds(
    (const __attribute__((address_space(1))) void*)g,
    (__attribute__((address_space(3))) void*)l, 16, 0, 0);
}

// ---------------- weight prep: LDS-tiled transpose fp32[K=512][N] -> bf16[N][512] ----
template<int N>
__global__ __launch_bounds__(256) void prep_w(const float* __restrict__ w, u16* __restrict__ wt){
  int tk = blockIdx.x / (N/64), tn = blockIdx.x % (N/64);
  int k0 = tk*64, n0 = tn*64;
  int t = threadIdx.x;
  __shared__ u16 lt[64][72];
  int row = t >> 2, slot = t & 3;
  const float* src = w + (size_t)(k0+row)*N + n0 + slot*16;
  #pragma unroll
  for (int j=0;j<16;++j)
    lt[row][slot*16+j] = f2bf(src[j]);
  __syncthreads();
  u16 tmp[16];
  #pragma unroll
  for (int j=0;j<16;++j) tmp[j] = lt[slot*16+j][row];
  *(u32x4*)(wt + (size_t)(n0+row)*512 + k0 + slot*16)     = *(u32x4*)tmp;
  *(u32x4*)(wt + (size_t)(n0+row)*512 + k0 + slot*16 + 8) = *(u32x4*)(tmp+8);
}

// ---------------- groupnorm stats: one block per (b,g) ----------------
__global__ __launch_bounds__(256) void gn_stats(const float* __restrict__ x, float* __restrict__ stats){
  int bid = blockIdx.x;            // b*32+g
  int b = bid >> 5, g = bid & 31;
  int t = threadIdx.x;
  const float* base = x + (size_t)b*SLEN*CDIM + g*16;
  float s1=0.f, s2=0.f;
  for (int s = t; s < SLEN; s += 256){
    const float4* p = (const float4*)(base + (size_t)s*CDIM);
    #pragma unroll
    for (int j=0;j<4;++j){
      float4 v = p[j];
      s1 += v.x+v.y+v.z+v.w;
      s2 += v.x*v.x + v.y*v.y + v.z*v.z + v.w*v.w;
    }
  }
  #pragma unroll
  for (int m=1;m<64;m<<=1){ s1 += __shfl_xor(s1,m); s2 += __shfl_xor(s2,m); }
  __shared__ float red[8];
  int wid = t>>6;
  if ((t&63)==0){ red[wid*2]=s1; red[wid*2+1]=s2; }
  __syncthreads();
  if (t==0){
    float a=0,c=0;
    #pragma unroll
    for (int w2=0;w2<4;++w2){ a+=red[w2*2]; c+=red[w2*2+1]; }
    float mean = a*(1.f/16384.f);
    float var  = c*(1.f/16384.f) - mean*mean;
    stats[bid*2]   = mean;
    stats[bid*2+1] = rsqrtf(var + 1e-5f);
  }
}

// ---------------- normalize + cast to bf16 ----------------
__global__ __launch_bounds__(256) void norm_cast(const float* __restrict__ x, const float* __restrict__ stats,
                        const float* __restrict__ scale, const float* __restrict__ bias,
                        u16* __restrict__ xn){
  int idx = blockIdx.x*256 + threadIdx.x;   // over 8192*32 (one 16-ch group per thread)
  int m = idx >> 5, g = idx & 31;
  int b = m >> 10;
  float mean = stats[(b*32+g)*2];
  float rstd = stats[(b*32+g)*2+1];
  const float* xp = x + (size_t)m*CDIM + g*16;
  const float* sp = scale + g*16;
  const float* bp = bias + g*16;
  short8 o0, o1;
  #pragma unroll
  for (int j=0;j<16;++j){
    float v = (xp[j]-mean)*rstd*sp[j] + bp[j];
    if (j<8) o0[j] = (short)f2bf(v); else o1[j-8] = (short)f2bf(v);
  }
  short8* dst = (short8*)(xn + (size_t)m*CDIM + g*16);
  dst[0]=o0; dst[1]=o1;
}

// ---------------- GEMM: C = A(MxK) * Bt(NxK)^T, bf16 in, fp32 acc ----------------
// Staging via global_load_lds (pre-swizzled source, linear LDS dest).
// 1-D grid with bijective XCD swizzle; NT = N/128 tiles.
#define BM 128
#define BN 128
#define BK 64

template<int EPI, int NT>
__global__ __launch_bounds__(256, 3) void gemm_bf16(
    const u16* __restrict__ A, const u16* __restrict__ Bt,
    const float* __restrict__ bias, const float* __restrict__ resid,
    float* __restrict__ outF,
    u16* __restrict__ qb, u16* __restrict__ kb, u16* __restrict__ vtb)
{
  const int K = CDIM;
  int t = threadIdx.x;
  int l = t & 63, wid = t >> 6;
  int g = l >> 4, c = l & 15;
  int wr = wid >> 1, wc = wid & 1;
  // bijective XCD swizzle (nwg % 8 == 0): each XCD gets contiguous M-chunk
  int nwg = gridDim.x;
  int cpx = nwg >> 3;
  int orig = blockIdx.x;
  int swz = (orig & 7)*cpx + (orig >> 3);
  int m0 = (swz / NT) * BM, n0 = (swz % NT) * BN;

  __shared__ __attribute__((aligned(16))) u16 ls[16384];   // 32 KB: lsA[0..8191], lsB[8192..]
  char* lsAc = (char*)ls; char* lsBc = (char*)(ls + 8192);

  f32x4 acc[4][4];
  #pragma unroll
  for (int i=0;i<4;++i)
    #pragma unroll
    for(int j=0;j<4;++j) acc[i][j] = (f32x4)0.f;

  // staging geometry: chunk = 1KB = 8 rows of [*][64] bf16 tile; 16 chunks per tile.
  // lane l covers row lrow=l>>3, 16B slot=l&7; source col pre-swizzled so that
  // LDS[row][slot] = A[row][(slot^(row&7))*8 ...] (matches read-side XOR swizzle).
  int lrow = l >> 3, slot = l & 7;
  int scol = ((slot ^ lrow) << 3);
  const int KT = K / BK;  // 8
  for (int kt=0; kt<KT; ++kt){
    __syncthreads();                    // all waves done reading previous tile
    int kbo = kt*BK;
    #pragma unroll
    for (int q2=0; q2<4; ++q2){
      int row = wid*32 + q2*8 + lrow;
      gld16(A  + (size_t)(m0+row)*K + kbo + scol, ls        + (wid*4+q2)*512);
      gld16(Bt + (size_t)(n0+row)*K + kbo + scol, ls + 8192 + (wid*4+q2)*512);
    }
    asm volatile("s_waitcnt vmcnt(0)" ::: "memory");
    __syncthreads();                    // staged tile visible to all waves
    #pragma unroll
    for (int kk=0; kk<2; ++kk){
      short8 af[4], bfr[4];
      #pragma unroll
      for (int i=0;i<4;++i){
        int rowA = wr*64 + i*16 + c;
        af[i]  = *(const short8*)(lsAc + rowA*128 + ((kk*4+g) ^ (rowA&7))*16);
        int rowB = wc*64 + i*16 + c;
        bfr[i] = *(const short8*)(lsBc + rowB*128 + ((kk*4+g) ^ (rowB&7))*16);
      }
      #pragma unroll
      for (int i=0;i<4;++i)
        #pragma unroll
        for (int j=0;j<4;++j)
          acc[i][j] = __builtin_amdgcn_mfma_f32_16x16x32_bf16(af[i], bfr[j], acc[i][j], 0,0,0);
    }
  }

  if (EPI == 0){
    int b = m0 >> 10, s0 = m0 & (SLEN-1);
    // ---- pass 1: stage full C tile (scaled+biased bf16) into lsC[128][128] ----
    __syncthreads();            // done reading lsA/lsB
    u16* lsC = ls;
    #pragma unroll
    for (int i=0;i<4;++i){
      int rl0 = wr*64 + i*16 + g*4;
      #pragma unroll
      for (int j=0;j<4;++j){
        int cl = wc*64 + j*16 + c;
        int gcol = n0 + cl;
        int jj = gcol % 192;
        float sc_ = (jj < 128) ? QK_SCALE : 1.0f;
        float bv = bias[gcol];
        #pragma unroll
        for (int r=0;r<4;++r)
          lsC[(rl0+r)*128 + cl] = f2bf((acc[i][j][r] + bv)*sc_);
      }
    }
    __syncthreads();
    // ---- pass 2: coalesced q/k stores, 16B per lane (non-temporal) ----
    #pragma unroll
    for (int cc=0; cc<8; ++cc){
      int ch = cc*256 + t;
      int rl = ch >> 4, slot2 = ch & 15;
      int cl = slot2*8;
      int gcol = n0 + cl;
      int h = gcol / 192, jj = gcol % 192;
      int s = s0 + rl;
      u32x4 vv = *(const u32x4*)(lsC + rl*128 + cl);
      size_t rowb = ((size_t)(b*NHEADS+h))*SLEN + s;
      if (jj < 64)       __builtin_nontemporal_store(vv, (u32x4*)(qb + rowb*HDIM + jj));
      else if (jj < 128) __builtin_nontemporal_store(vv, (u32x4*)(kb + rowb*HDIM + (jj-64)));
    }
    // ---- pass 3: V via padded LDS transpose -> coalesced 16B chunks along s ----
    int blk3 = (n0 >> 7) % 3;   // 0: no v-cols; 1: v at local 0-63; 2: v at local 64-127
    if (blk3 != 0){
      __syncthreads();          // pass-2 reads of lsC done; reuse as lsV
      u16* lsV = ls;            // [64][136] padded
      #pragma unroll
      for (int i=0;i<4;++i){
        int rl0 = wr*64 + i*16 + g*4;
        #pragma unroll
        for (int j=0;j<4;++j){
          int cl = wc*64 + j*16 + c;
          int jj = (n0 + cl) % 192;
          if (jj >= 128){
            #pragma unroll
            for (int r=0;r<4;++r)
              lsV[(jj-128)*136 + rl0 + r] = f2bf(acc[i][j][r] + bias[n0+cl]);
          }
        }
      }
      __syncthreads();
      int hv = (n0 + ((blk3==1)?0:64)) / 192;
      size_t vbase = ((size_t)(b*NHEADS+hv))*HDIM*SLEN;
      #pragma unroll
      for (int cc=0; cc<4; ++cc){
        int chunk = cc*256 + t;        // 1024 chunks of 8 u16
        int d = chunk >> 4, so = (chunk & 15)*8;
        u32x4 vv = *(const u32x4*)(lsV + d*136 + so);
        __builtin_nontemporal_store(vv, (u32x4*)(vtb + vbase + (size_t)d*SLEN + s0 + so));
      }
    }
  } else {
    #pragma unroll
    for (int i=0;i<4;++i){
      int grow = m0 + wr*64 + i*16 + g*4;
      #pragma unroll
      for (int j=0;j<4;++j){
        int gcol = n0 + wc*64 + j*16 + c;
        float bv = bias[gcol];
        #pragma unroll
        for (int r=0;r<4;++r){
          size_t off = (size_t)(grow+r)*CDIM + gcol;
          float rv = __builtin_nontemporal_load(&resid[off]);
          __builtin_nontemporal_store(acc[i][j][r] + bv + rv, &outF[off]);  // SKIP_SCALE == 1.0
        }
      }
    }
  }
}

// ---------------- fused flash attention: swapped-QK^T 32x32 structure (m214 port) ----
#define PV_KS(PT, QOFF, KS) { \
    u32 A0 = pk2(PT[QOFF+0], PT[QOFF+1]); \
    u32 A1 = pk2(PT[QOFF+2], PT[QOFF+3]); \
    u32 B0 = pk2(PT[QOFF+4], PT[QOFF+5]); \
    u32 B1 = pk2(PT[QOFF+6], PT[QOFF+7]); \
    u32 A0s = __shfl_xor(A0,32), A1s = __shfl_xor(A1,32); \
    u32 B0s = __shfl_xor(B0,32), B1s = __shfl_xor(B1,32); \
    uint4 w; \
    w.x = hi ? B0s : A0;  w.y = hi ? B1s : A1; \
    w.z = hi ? B0  : A0s; w.w = hi ? B1  : A1s; \
    short8 fP; __builtin_memcpy(&fP, &w, 16); \
    o0 = __builtin_amdgcn_mfma_f32_32x32x16_bf16(fV0[KS], fP, o0, 0,0,0); \
    o1 = __builtin_amdgcn_mfma_f32_32x32x16_bf16(fV1[KS], fP, o1, 0,0,0); }

__global__ __launch_bounds__(256, 2) void attn_fused(const u16* __restrict__ qg,
  const u16* __restrict__ kg, const u16* __restrict__ vtg, u16* __restrict__ og)
{
  int bid = blockIdx.x;
  // XCD-contiguous swizzle: each XCD works on 8 consecutive bh (2MB K/V -> L2-fits)
  int nid = (bid & 7)*64 + (bid >> 3);
  int bh = nid >> 3, qi = nid & 7;
  int t = threadIdx.x, l = t & 63, wid = t >> 6;
  int q = l & 31, hi = l >> 5;
  int q0 = qi*128 + wid*32;

  const u16* qrow = qg + ((size_t)bh*SLEN + q0 + q)*HDIM + hi*8;
  short8 fQ[4];
  #pragma unroll
  for (int ds=0; ds<4; ++ds) fQ[ds] = *(const short8*)(qrow + ds*16);

  f32x16 o0, o1;
  #pragma unroll
  for (int r=0;r<16;++r){ o0[r]=0.f; o1[r]=0.f; }
  float mr = -1e30f, lsum = 0.f;

  const u16* kbase = kg  + (size_t)bh*SLEN*HDIM;
  const u16* vbase = vtg + (size_t)bh*HDIM*SLEN;

  for (int kv=0; kv<16; ++kv){
    const u16* kp = kbase + (size_t)kv*64*HDIM + hi*8;
    short8 fK0[4], fK1[4];
    #pragma unroll
    for (int ds=0; ds<4; ++ds){
      fK0[ds] = *(const short8*)(kp + (size_t)q*HDIM + ds*16);
      fK1[ds] = *(const short8*)(kp + (size_t)(q+32)*HDIM + ds*16);
    }
    f32x16 p0, p1;
    #pragma unroll
    for (int r=0;r<16;++r){ p0[r]=0.f; p1[r]=0.f; }
    #pragma unroll
    for (int ds=0; ds<4; ++ds){
      p0 = __builtin_amdgcn_mfma_f32_32x32x16_bf16(fK0[ds], fQ[ds], p0, 0,0,0);
      p1 = __builtin_amdgcn_mfma_f32_32x32x16_bf16(fK1[ds], fQ[ds], p1, 0,0,0);
    }
    const u16* vp = vbase + kv*64 + hi*8;
    short8 fV0[4], fV1[4];
    #pragma unroll
    for (int ks=0; ks<4; ++ks){
      fV0[ks] = *(const short8*)(vp + (size_t)q*SLEN + ks*16);
      fV1[ks] = *(const short8*)(vp + (size_t)(q+32)*SLEN + ks*16);
    }
    float a8[8];
    #pragma unroll
    for (int r=0;r<8;++r)
      a8[r] = fmaxf(fmaxf(p0[r],p0[r+8]), fmaxf(p1[r],p1[r+8]));
    #pragma unroll
    for (int s=4;s>0;s>>=1)
      #pragma unroll
      for (int r=0;r<4;++r) if (r<s) a8[r] = fmaxf(a8[r], a8[r+s]);
    float tmax = fmaxf(a8[0], __shfl_xor(a8[0], 32));
    float mn = fmaxf(mr, tmax);
    float alpha = __expf(mr - mn);
    mr = mn;
    #pragma unroll
    for (int r=0;r<16;++r){ p0[r] = __expf(p0[r]-mn); p1[r] = __expf(p1[r]-mn); }
    float s8[8];
    #pragma unroll
    for (int r=0;r<8;++r) s8[r] = (p0[r]+p0[r+8]) + (p1[r]+p1[r+8]);
    #pragma unroll
    for (int s=4;s>0;s>>=1)
      #pragma unroll
      for (int r=0;r<4;++r) if (r<s) s8[r] += s8[r+s];
    float rs = s8[0] + __shfl_xor(s8[0], 32);
    lsum = lsum*alpha + rs;
    #pragma unroll
    for (int r=0;r<16;++r){ o0[r]*=alpha; o1[r]*=alpha; }
    PV_KS(p0, 0, 0)
    PV_KS(p0, 8, 1)
    PV_KS(p1, 0, 2)
    PV_KS(p1, 8, 3)
  }

  float inv = 1.f / lsum;
  int b = bh >> 3, h = bh & 7;
  u16* obase = og + ((size_t)b*SLEN + q0 + q)*CDIM + h*HDIM;
  #pragma unroll
  for (int pr=0; pr<8; ++pr){
    int d = ((2*pr)&3) + 8*(pr>>1) + 4*hi;
    *(u32*)(obase + d)      = pk2(o0[2*pr]*inv, o0[2*pr+1]*inv);
    *(u32*)(obase + 32 + d) = pk2(o1[2*pr]*inv, o1[2*pr+1]*inv);
  }
}

extern "C" void kernel_launch(void* const* d_in, const int* in_sizes, int n_in,
                              void* d_out, int out_size, void* d_ws, size_t ws_size,
                              hipStream_t stream){
  const float* x      = (const float*)d_in[0];
  const float* nscale = (const float*)d_in[1];
  const float* nbias  = (const float*)d_in[2];
  const float* wqkv   = (const float*)d_in[3];
  const float* bqkv   = (const float*)d_in[4];
  const float* wout   = (const float*)d_in[5];
  const float* bout   = (const float*)d_in[6];
  float* out = (float*)d_out;

  char* ws = (char*)d_ws;
  size_t off = 0;
  auto alloc = [&](size_t bytes){ void* p = ws + off; off += (bytes + 255) & ~255ull; return p; };
  float* stats  = (float*)alloc(256*2*sizeof(float));
  u16* wqkv_t = (u16*)alloc((size_t)NQKV*CDIM*2);
  u16* wout_t = (u16*)alloc((size_t)CDIM*CDIM*2);
  u16* xn     = (u16*)alloc((size_t)MROWS*CDIM*2);
  u16* qb     = (u16*)alloc((size_t)MROWS*CDIM*2);
  u16* kb     = (u16*)alloc((size_t)MROWS*CDIM*2);
  u16* vtb    = (u16*)alloc((size_t)MROWS*CDIM*2);
  u16* ob     = (u16*)alloc((size_t)MROWS*CDIM*2);

  prep_w<NQKV><<<dim3(8*(NQKV/64)), dim3(256), 0, stream>>>(wqkv, wqkv_t);
  prep_w<CDIM><<<dim3(8*(CDIM/64)), dim3(256), 0, stream>>>(wout, wout_t);
  gn_stats <<<dim3(256), dim3(256), 0, stream>>>(x, stats);
  norm_cast<<<dim3((MROWS*32)/256), dim3(256), 0, stream>>>(x, stats, nscale, nbias, xn);
  gemm_bf16<0,12><<<dim3(768), dim3(256), 0, stream>>>(xn, wqkv_t, bqkv, nullptr, nullptr, qb, kb, vtb);
  attn_fused<<<dim3(512), dim3(256), 0, stream>>>(qb, kb, vtb, ob);
  gemm_bf16<1,4><<<dim3(256), dim3(256), 0, stream>>>(ob, wout_t, bout, x, out, nullptr, nullptr, nullptr);
}